// Round 1
// baseline (7031.141 us; speedup 1.0000x reference)
//
#include <hip/hip_runtime.h>
#include <cstdint>
#include <cstddef>

#define TT   512
#define BATCH 64
#define HID  1024
#define KDIM 1024

typedef short bf16x8 __attribute__((ext_vector_type(8)));
typedef float f32x4 __attribute__((ext_vector_type(4)));

__device__ __forceinline__ unsigned short f2b(float f) {
    unsigned int u = __float_as_uint(f);
    u = (u + 0x7fffu + ((u >> 16) & 1u)) >> 16;
    return (unsigned short)u;
}

// ---------------------------------------------------------------------------
// init: concat biases, zero h buffers + barrier state
// ---------------------------------------------------------------------------
__global__ __launch_bounds__(256) void k_init(
    const float* __restrict__ b_ir, const float* __restrict__ b_iz, const float* __restrict__ b_in,
    const float* __restrict__ b_hr, const float* __restrict__ b_hz, const float* __restrict__ b_hn,
    float* __restrict__ bias_x, float* __restrict__ bias_h,
    unsigned short* __restrict__ hbf, int* __restrict__ counters, int* __restrict__ epoch)
{
    int gid = blockIdx.x * 256 + threadIdx.x;          // grid 64x256 = 16384
    if (gid < HID) {
        bias_x[gid]        = b_ir[gid];
        bias_x[HID + gid]  = b_iz[gid];
        bias_x[2*HID + gid]= b_in[gid];
        bias_h[gid]        = b_hr[gid];
        bias_h[HID + gid]  = b_hz[gid];
        bias_h[2*HID + gid]= b_hn[gid];
    }
    // zero both h bf16 buffers: 2*64*1024 ushorts = 32768 ushort4
    ushort4 z4 = make_ushort4(0, 0, 0, 0);
    ushort4* p = reinterpret_cast<ushort4*>(hbf);
    p[2*gid]   = z4;
    p[2*gid+1] = z4;
    if (gid < 64)  counters[gid * 32] = 0;
    if (gid == 64) *epoch = 0;
}

// ---------------------------------------------------------------------------
// transpose W[k][j] (fp32) -> wT[n][k] (bf16), n = gate*1024 + j
// grid (32, 32, 6), block (32, 8)
// ---------------------------------------------------------------------------
__global__ __launch_bounds__(256) void k_trans(
    const float* __restrict__ w0, const float* __restrict__ w1, const float* __restrict__ w2,
    const float* __restrict__ w3, const float* __restrict__ w4, const float* __restrict__ w5,
    unsigned short* __restrict__ wxT, unsigned short* __restrict__ whT)
{
    __shared__ float tile[32][33];
    int z = blockIdx.z;
    const float* src = (z == 0) ? w0 : (z == 1) ? w1 : (z == 2) ? w2
                     : (z == 3) ? w3 : (z == 4) ? w4 : w5;
    unsigned short* dst = (z < 3) ? (wxT + (size_t)z * HID * KDIM)
                                  : (whT + (size_t)(z - 3) * HID * KDIM);
    int kb = blockIdx.x * 32, jb = blockIdx.y * 32;
    int tx = threadIdx.x, ty = threadIdx.y;
    #pragma unroll
    for (int p = 0; p < 4; p++)
        tile[tx][ty + 8*p] = src[(size_t)(kb + ty + 8*p) * HID + jb + tx];
    __syncthreads();
    #pragma unroll
    for (int p = 0; p < 4; p++) {
        int n = jb + ty + 8*p;
        dst[(size_t)n * KDIM + kb + tx] = f2b(tile[ty + 8*p][tx]);
    }
}

// ---------------------------------------------------------------------------
// GEMM A: gates = x @ [W_ir|W_iz|W_in] + bias.  M=32768, N=3072, K=1024.
// 128x128 tile, BK=64, 256 thr (4 waves 2x2, each 64x64 = 4x4 mfma tiles).
// Output scattered time-major: row R=b*512+t -> orow = t*64+b.
// g0 -> ggr (ws), g1 -> ggz (ws), g2 -> d_out (gn, consumed in-place later).
// ---------------------------------------------------------------------------
#define BM 128
#define BN 128
#define LDA 72   // 64 + 8 pad, in ushorts (144 B rows, 16B-aligned)

__global__ __launch_bounds__(256, 2) void k_gemm_x(
    const float* __restrict__ x,            // [32768][1024] fp32
    const unsigned short* __restrict__ wxT, // [3072][1024] bf16
    const float* __restrict__ biasx,        // [3072]
    float* __restrict__ ggr, float* __restrict__ ggz, float* __restrict__ ggn)
{
    __shared__ unsigned short lA[BM * LDA];
    __shared__ unsigned short lB[BN * LDA];
    int tid  = threadIdx.x;
    int wave = tid >> 6, lane = tid & 63;
    int l16  = lane & 15, lhi = lane >> 4;
    int rbase = blockIdx.x * BM;
    int nbase = blockIdx.y * BN;
    int wm = (wave >> 1) * 64, wn = (wave & 1) * 64;

    f32x4 acc[4][4];
    for (int a = 0; a < 4; a++)
        for (int b = 0; b < 4; b++)
            acc[a][b] = f32x4{0.f, 0.f, 0.f, 0.f};

    int arow = tid >> 4;          // 16 rows/pass, 8 passes
    int acol = (tid & 15) * 4;    // float4 within 64 floats
    int brow = tid >> 3;          // 32 rows/pass, 4 passes
    int bcol = (tid & 7) * 8;     // 8 shorts within 64

    for (int kb = 0; kb < KDIM; kb += 64) {
        __syncthreads();
        #pragma unroll
        for (int p = 0; p < 8; p++) {
            int r = p * 16 + arow;
            float4 v = *(const float4*)(x + (size_t)(rbase + r) * KDIM + kb + acol);
            ushort4 s;
            s.x = f2b(v.x); s.y = f2b(v.y); s.z = f2b(v.z); s.w = f2b(v.w);
            *(ushort4*)(lA + r * LDA + acol) = s;
        }
        #pragma unroll
        for (int p = 0; p < 4; p++) {
            int r = p * 32 + brow;
            bf16x8 v = *(const bf16x8*)(wxT + (size_t)(nbase + r) * KDIM + kb + bcol);
            *(bf16x8*)(lB + r * LDA + bcol) = v;
        }
        __syncthreads();
        #pragma unroll
        for (int kk = 0; kk < 2; kk++) {
            bf16x8 af[4], bfr[4];
            #pragma unroll
            for (int mt = 0; mt < 4; mt++)
                af[mt] = *(const bf16x8*)(lA + (wm + mt*16 + l16) * LDA + kk*32 + lhi*8);
            #pragma unroll
            for (int nt = 0; nt < 4; nt++)
                bfr[nt] = *(const bf16x8*)(lB + (wn + nt*16 + l16) * LDA + kk*32 + lhi*8);
            #pragma unroll
            for (int mt = 0; mt < 4; mt++)
                #pragma unroll
                for (int nt = 0; nt < 4; nt++)
                    acc[mt][nt] = __builtin_amdgcn_mfma_f32_16x16x32_bf16(
                        af[mt], bfr[nt], acc[mt][nt], 0, 0, 0);
        }
    }
    // epilogue: C/D layout col=lane&15 (N), row=(lane>>4)*4+i (M)
    #pragma unroll
    for (int nt = 0; nt < 4; nt++) {
        int n = nbase + wn + nt*16 + l16;
        float bv = biasx[n];
        int g = n >> 10;
        int j = n & 1023;
        float* outp = (g == 0) ? ggr : (g == 1) ? ggz : ggn;
        #pragma unroll
        for (int mt = 0; mt < 4; mt++) {
            #pragma unroll
            for (int i = 0; i < 4; i++) {
                int R = rbase + wm + mt*16 + lhi*4 + i;        // R = b*512 + t
                size_t orow = (size_t)((R & 511) * BATCH + (R >> 9));
                outp[orow * HID + j] = acc[mt][nt][i] + bv;
            }
        }
    }
}

// ---------------------------------------------------------------------------
// Recurrence: persistent, 64 blocks x 256 thr (co-resident: 1 block/CU).
// Block = 16 cols (j), wave = 16 batch rows. All 3 gates' recurrent weight
// fragments live in registers (96 x bf16x8). Grid barrier per step.
// ---------------------------------------------------------------------------
__global__ __launch_bounds__(256, 1) void k_recur(
    const float* __restrict__ ggr, const float* __restrict__ ggz,
    float* __restrict__ dout,                // [T][B][H] (gn preloaded) + tail [B][H]
    const unsigned short* __restrict__ whT,  // [3072][1024] bf16
    const float* __restrict__ biash,         // [3072]
    unsigned short* __restrict__ hbf,        // [2][64][1024] bf16
    int* __restrict__ counters, int* __restrict__ epoch)
{
    int tid  = threadIdx.x;
    int wave = tid >> 6, lane = tid & 63;
    int l16  = lane & 15, lhi = lane >> 4;
    int blk  = blockIdx.x;
    int j    = blk * 16 + l16;
    int mbase = wave * 16;
    int b0    = mbase + lhi * 4;   // batch row of acc reg 0

    // loop-invariant weight fragments -> registers (B-frag: n=lane&15, k=lhi*8+i)
    bf16x8 wr[32], wz[32], wn[32];
    {
        const unsigned short* base = whT + (size_t)j * KDIM + lhi * 8;
        #pragma unroll
        for (int kk = 0; kk < 32; kk++) {
            wr[kk] = *(const bf16x8*)(base + kk*32);
            wz[kk] = *(const bf16x8*)(base + kk*32 + (size_t)HID * KDIM);
            wn[kk] = *(const bf16x8*)(base + kk*32 + (size_t)2 * HID * KDIM);
        }
    }
    float bhr = biash[j], bhz = biash[HID + j], bhn = biash[2*HID + j];

    float hp[4] = {0.f, 0.f, 0.f, 0.f};
    float cgr[4], cgz[4], cgn[4];
    {
        size_t g0 = (size_t)b0 * HID + j;   // t = 0
        #pragma unroll
        for (int i = 0; i < 4; i++) {
            cgr[i] = ggr[g0 + (size_t)i * HID];
            cgz[i] = ggz[g0 + (size_t)i * HID];
            cgn[i] = dout[g0 + (size_t)i * HID];
        }
    }

    #pragma unroll 1
    for (int t = 0; t < TT; t++) {
        // prefetch next step's gates (hides HBM latency behind MFMA + barrier)
        float ngr[4] = {0,0,0,0}, ngz[4] = {0,0,0,0}, ngn[4] = {0,0,0,0};
        if (t + 1 < TT) {
            size_t g1 = (size_t)((t + 1) * BATCH + b0) * HID + j;
            #pragma unroll
            for (int i = 0; i < 4; i++) {
                ngr[i] = ggr[g1 + (size_t)i * HID];
                ngz[i] = ggz[g1 + (size_t)i * HID];
                ngn[i] = dout[g1 + (size_t)i * HID];
            }
        }

        const unsigned short* hrow = hbf + (size_t)(t & 1) * BATCH * HID
                                   + (size_t)(mbase + l16) * HID + lhi * 8;
        f32x4 ar{0,0,0,0}, az{0,0,0,0}, an{0,0,0,0};
        #pragma unroll
        for (int kk = 0; kk < 32; kk++) {
            bf16x8 af = *(const bf16x8*)(hrow + kk * 32);
            ar = __builtin_amdgcn_mfma_f32_16x16x32_bf16(af, wr[kk], ar, 0, 0, 0);
            az = __builtin_amdgcn_mfma_f32_16x16x32_bf16(af, wz[kk], az, 0, 0, 0);
            an = __builtin_amdgcn_mfma_f32_16x16x32_bf16(af, wn[kk], an, 0, 0, 0);
        }

        unsigned short* hnext = hbf + (size_t)((t + 1) & 1) * BATCH * HID;
        size_t orow = (size_t)(t * BATCH + b0) * HID + j;
        #pragma unroll
        for (int i = 0; i < 4; i++) {
            float r  = 1.f / (1.f + __expf(-(cgr[i] + ar[i] + bhr)));
            float z  = 1.f / (1.f + __expf(-(cgz[i] + az[i] + bhz)));
            float nv = cgn[i] + r * (an[i] + bhn);
            float th = 1.f - 2.f / (1.f + __expf(2.f * nv));   // tanh(nv)
            float hv = (1.f - z) * th + z * hp[i];
            hp[i] = hv;
            dout[orow + (size_t)i * HID] = hv;
            hnext[(size_t)(b0 + i) * HID + j] = f2b(hv);
        }
        if (t == TT - 1) {
            #pragma unroll
            for (int i = 0; i < 4; i++)
                dout[(size_t)TT * BATCH * HID + (size_t)(b0 + i) * HID + j] = hp[i];
        }
        #pragma unroll
        for (int i = 0; i < 4; i++) { cgr[i] = ngr[i]; cgz[i] = ngz[i]; cgn[i] = ngn[i]; }

        // ---- grid barrier (sense via epoch counter) ----
        __syncthreads();
        if (tid == 0)
            __hip_atomic_store(&counters[blk * 32], t + 1,
                               __ATOMIC_RELEASE, __HIP_MEMORY_SCOPE_AGENT);
        if (blk == 0) {
            if (tid < 64) {
                while (__hip_atomic_load(&counters[tid * 32],
                                         __ATOMIC_ACQUIRE, __HIP_MEMORY_SCOPE_AGENT) < t + 1)
                    __builtin_amdgcn_s_sleep(1);
            }
            __syncthreads();
            if (tid == 0)
                __hip_atomic_store(epoch, t + 1,
                                   __ATOMIC_RELEASE, __HIP_MEMORY_SCOPE_AGENT);
        }
        if (tid == 0) {
            while (__hip_atomic_load(epoch,
                                     __ATOMIC_ACQUIRE, __HIP_MEMORY_SCOPE_AGENT) < t + 1)
                __builtin_amdgcn_s_sleep(1);
        }
        __syncthreads();
    }
}

// ---------------------------------------------------------------------------
extern "C" void kernel_launch(void* const* d_in, const int* in_sizes, int n_in,
                              void* d_out, int out_size, void* d_ws, size_t ws_size,
                              hipStream_t stream)
{
    const float* x    = (const float*)d_in[0];
    const float* W_ir = (const float*)d_in[1];
    const float* b_ir = (const float*)d_in[2];
    const float* W_hr = (const float*)d_in[3];
    const float* b_hr = (const float*)d_in[4];
    const float* W_iz = (const float*)d_in[5];
    const float* b_iz = (const float*)d_in[6];
    const float* W_hz = (const float*)d_in[7];
    const float* b_hz = (const float*)d_in[8];
    const float* W_in = (const float*)d_in[9];
    const float* b_in = (const float*)d_in[10];
    const float* W_hn = (const float*)d_in[11];
    const float* b_hn = (const float*)d_in[12];
    float* out = (float*)d_out;

    char* ws = (char*)d_ws;
    size_t off = 0;
    auto alloc = [&](size_t bytes) -> char* {
        char* p = ws + off;
        off += (bytes + 255) & ~(size_t)255;
        return p;
    };
    float*          ggr      = (float*)alloc((size_t)TT * BATCH * HID * 4);
    float*          ggz      = (float*)alloc((size_t)TT * BATCH * HID * 4);
    unsigned short* wxT      = (unsigned short*)alloc((size_t)3 * HID * KDIM * 2);
    unsigned short* whT      = (unsigned short*)alloc((size_t)3 * HID * KDIM * 2);
    float*          bias_x   = (float*)alloc(3 * HID * 4);
    float*          bias_h   = (float*)alloc(3 * HID * 4);
    unsigned short* hbf      = (unsigned short*)alloc((size_t)2 * BATCH * HID * 2);
    int*            counters = (int*)alloc(64 * 32 * 4);
    int*            epoch    = (int*)alloc(128);

    k_init<<<64, 256, 0, stream>>>(b_ir, b_iz, b_in, b_hr, b_hz, b_hn,
                                   bias_x, bias_h, hbf, counters, epoch);
    k_trans<<<dim3(32, 32, 6), dim3(32, 8), 0, stream>>>(W_ir, W_iz, W_in,
                                                         W_hr, W_hz, W_hn, wxT, whT);
    k_gemm_x<<<dim3(256, 24), 256, 0, stream>>>(x, wxT, bias_x, ggr, ggz, out);
    k_recur<<<64, 256, 0, stream>>>(ggr, ggz, out, whT, bias_h, hbf, counters, epoch);
}

// Round 2
// 5923.391 us; speedup vs baseline: 1.1870x; 1.1870x over previous
//
#include <hip/hip_runtime.h>
#include <cstdint>
#include <cstddef>

#define TT   512
#define BATCH 64
#define HID  1024
#define KDIM 1024

typedef short bf16x8 __attribute__((ext_vector_type(8)));
typedef float f32x4 __attribute__((ext_vector_type(4)));

__device__ __forceinline__ unsigned short f2b(float f) {
    unsigned int u = __float_as_uint(f);
    u = (u + 0x7fffu + ((u >> 16) & 1u)) >> 16;
    return (unsigned short)u;
}

// ---------------------------------------------------------------------------
// init: concat biases, zero h buffers + barrier state
// ---------------------------------------------------------------------------
__global__ __launch_bounds__(256) void k_init(
    const float* __restrict__ b_ir, const float* __restrict__ b_iz, const float* __restrict__ b_in,
    const float* __restrict__ b_hr, const float* __restrict__ b_hz, const float* __restrict__ b_hn,
    float* __restrict__ bias_x, float* __restrict__ bias_h,
    unsigned short* __restrict__ hbf, int* __restrict__ arrive)
{
    int gid = blockIdx.x * 256 + threadIdx.x;          // grid 64x256 = 16384
    if (gid < HID) {
        bias_x[gid]        = b_ir[gid];
        bias_x[HID + gid]  = b_iz[gid];
        bias_x[2*HID + gid]= b_in[gid];
        bias_h[gid]        = b_hr[gid];
        bias_h[HID + gid]  = b_hz[gid];
        bias_h[2*HID + gid]= b_hn[gid];
    }
    // zero both h bf16 buffers: 2*64*1024 ushorts = 32768 ushort4
    ushort4 z4 = make_ushort4(0, 0, 0, 0);
    ushort4* p = reinterpret_cast<ushort4*>(hbf);
    p[2*gid]   = z4;
    p[2*gid+1] = z4;
    if (gid == 0) *arrive = 0;
}

// ---------------------------------------------------------------------------
// transpose W[k][j] (fp32) -> wT[n][k] (bf16), n = gate*1024 + j
// grid (32, 32, 6), block (32, 8)
// ---------------------------------------------------------------------------
__global__ __launch_bounds__(256) void k_trans(
    const float* __restrict__ w0, const float* __restrict__ w1, const float* __restrict__ w2,
    const float* __restrict__ w3, const float* __restrict__ w4, const float* __restrict__ w5,
    unsigned short* __restrict__ wxT, unsigned short* __restrict__ whT)
{
    __shared__ float tile[32][33];
    int z = blockIdx.z;
    const float* src = (z == 0) ? w0 : (z == 1) ? w1 : (z == 2) ? w2
                     : (z == 3) ? w3 : (z == 4) ? w4 : w5;
    unsigned short* dst = (z < 3) ? (wxT + (size_t)z * HID * KDIM)
                                  : (whT + (size_t)(z - 3) * HID * KDIM);
    int kb = blockIdx.x * 32, jb = blockIdx.y * 32;
    int tx = threadIdx.x, ty = threadIdx.y;
    #pragma unroll
    for (int p = 0; p < 4; p++)
        tile[tx][ty + 8*p] = src[(size_t)(kb + ty + 8*p) * HID + jb + tx];
    __syncthreads();
    #pragma unroll
    for (int p = 0; p < 4; p++) {
        int n = jb + ty + 8*p;
        dst[(size_t)n * KDIM + kb + tx] = f2b(tile[ty + 8*p][tx]);
    }
}

// ---------------------------------------------------------------------------
// GEMM A: gates = x @ [W_ir|W_iz|W_in] + bias.  M=32768, N=3072, K=1024.
// 128x128 tile, BK=64, 256 thr (4 waves 2x2, each 64x64 = 4x4 mfma tiles).
// Output scattered time-major: row R=b*512+t -> orow = t*64+b.
// g0 -> ggr (ws), g1 -> ggz (ws), g2 -> d_out (gn, consumed in-place later).
// ---------------------------------------------------------------------------
#define BM 128
#define BN 128
#define LDA 72   // 64 + 8 pad, in ushorts (144 B rows, 16B-aligned)

__global__ __launch_bounds__(256, 2) void k_gemm_x(
    const float* __restrict__ x,            // [32768][1024] fp32
    const unsigned short* __restrict__ wxT, // [3072][1024] bf16
    const float* __restrict__ biasx,        // [3072]
    float* __restrict__ ggr, float* __restrict__ ggz, float* __restrict__ ggn)
{
    __shared__ unsigned short lA[BM * LDA];
    __shared__ unsigned short lB[BN * LDA];
    int tid  = threadIdx.x;
    int wave = tid >> 6, lane = tid & 63;
    int l16  = lane & 15, lhi = lane >> 4;
    int rbase = blockIdx.x * BM;
    int nbase = blockIdx.y * BN;
    int wm = (wave >> 1) * 64, wn = (wave & 1) * 64;

    f32x4 acc[4][4];
    for (int a = 0; a < 4; a++)
        for (int b = 0; b < 4; b++)
            acc[a][b] = f32x4{0.f, 0.f, 0.f, 0.f};

    int arow = tid >> 4;          // 16 rows/pass, 8 passes
    int acol = (tid & 15) * 4;    // float4 within 64 floats
    int brow = tid >> 3;          // 32 rows/pass, 4 passes
    int bcol = (tid & 7) * 8;     // 8 shorts within 64

    for (int kb = 0; kb < KDIM; kb += 64) {
        __syncthreads();
        #pragma unroll
        for (int p = 0; p < 8; p++) {
            int r = p * 16 + arow;
            float4 v = *(const float4*)(x + (size_t)(rbase + r) * KDIM + kb + acol);
            ushort4 s;
            s.x = f2b(v.x); s.y = f2b(v.y); s.z = f2b(v.z); s.w = f2b(v.w);
            *(ushort4*)(lA + r * LDA + acol) = s;
        }
        #pragma unroll
        for (int p = 0; p < 4; p++) {
            int r = p * 32 + brow;
            bf16x8 v = *(const bf16x8*)(wxT + (size_t)(nbase + r) * KDIM + kb + bcol);
            *(bf16x8*)(lB + r * LDA + bcol) = v;
        }
        __syncthreads();
        #pragma unroll
        for (int kk = 0; kk < 2; kk++) {
            bf16x8 af[4], bfr[4];
            #pragma unroll
            for (int mt = 0; mt < 4; mt++)
                af[mt] = *(const bf16x8*)(lA + (wm + mt*16 + l16) * LDA + kk*32 + lhi*8);
            #pragma unroll
            for (int nt = 0; nt < 4; nt++)
                bfr[nt] = *(const bf16x8*)(lB + (wn + nt*16 + l16) * LDA + kk*32 + lhi*8);
            #pragma unroll
            for (int mt = 0; mt < 4; mt++)
                #pragma unroll
                for (int nt = 0; nt < 4; nt++)
                    acc[mt][nt] = __builtin_amdgcn_mfma_f32_16x16x32_bf16(
                        af[mt], bfr[nt], acc[mt][nt], 0, 0, 0);
        }
    }
    // epilogue: C/D layout col=lane&15 (N), row=(lane>>4)*4+i (M)
    #pragma unroll
    for (int nt = 0; nt < 4; nt++) {
        int n = nbase + wn + nt*16 + l16;
        float bv = biasx[n];
        int g = n >> 10;
        int j = n & 1023;
        float* outp = (g == 0) ? ggr : (g == 1) ? ggz : ggn;
        #pragma unroll
        for (int mt = 0; mt < 4; mt++) {
            #pragma unroll
            for (int i = 0; i < 4; i++) {
                int R = rbase + wm + mt*16 + lhi*4 + i;        // R = b*512 + t
                size_t orow = (size_t)((R & 511) * BATCH + (R >> 9));
                outp[orow * HID + j] = acc[mt][nt][i] + bv;
            }
        }
    }
}

// ---------------------------------------------------------------------------
// Recurrence: persistent, 64 blocks x 256 thr (1 block/CU, co-resident).
// Block = 16 cols (j = blk*16 + l16). Waves split K (256 each): only 24
// weight frags/lane -> register-resident. Cross-wave reduce via LDS.
// Flattened grid barrier: one release fence + one fire-and-forget atomicAdd
// + relaxed bypassing spin + one acquire fence per step.
// ---------------------------------------------------------------------------
__global__ __launch_bounds__(256, 1) void k_recur(
    const float* __restrict__ ggr, const float* __restrict__ ggz,
    float* __restrict__ dout,                // [T][B][H] (gn preloaded) + tail [B][H]
    const unsigned short* __restrict__ whT,  // [3072][1024] bf16
    const float* __restrict__ biash,         // [3072]
    unsigned short* __restrict__ hbf,        // [2][64][1024] bf16
    int* __restrict__ arrive)
{
    __shared__ f32x4 red[3][4][4][64];       // gate, mtile, src_wave, lane (48 KB)

    int tid  = threadIdx.x;
    int w    = tid >> 6, lane = tid & 63;    // wave = K-quarter owner, own mtile = w
    int l16  = lane & 15, lhi = lane >> 4;
    int blk  = blockIdx.x;
    int j    = blk * 16 + l16;
    int kofs = w * 256 + lhi * 8;            // this lane's K base within whT / h rows
    int b0   = w * 16 + lhi * 4;             // batch row of own-mtile acc reg 0

    // loop-invariant weight fragments -> registers (24 x bf16x8 = 96 VGPR)
    bf16x8 wr[8], wz[8], wn[8];
    {
        const unsigned short* base = whT + (size_t)j * KDIM + kofs;
        #pragma unroll
        for (int kk = 0; kk < 8; kk++) {
            wr[kk] = *(const bf16x8*)(base + kk*32);
            wz[kk] = *(const bf16x8*)(base + kk*32 + (size_t)HID * KDIM);
            wn[kk] = *(const bf16x8*)(base + kk*32 + (size_t)2 * HID * KDIM);
        }
    }
    float bhr = biash[j], bhz = biash[HID + j], bhn = biash[2*HID + j];

    float hp[4] = {0.f, 0.f, 0.f, 0.f};
    float cgr[4], cgz[4], cgn[4];
    {
        size_t g0 = (size_t)b0 * HID + j;   // t = 0
        #pragma unroll
        for (int i = 0; i < 4; i++) {
            cgr[i] = ggr[g0 + (size_t)i * HID];
            cgz[i] = ggz[g0 + (size_t)i * HID];
            cgn[i] = dout[g0 + (size_t)i * HID];
        }
    }

    #pragma unroll 1
    for (int t = 0; t < TT; t++) {
        // prefetch next step's gates (hides HBM latency behind MFMA)
        float ngr[4] = {0,0,0,0}, ngz[4] = {0,0,0,0}, ngn[4] = {0,0,0,0};
        if (t + 1 < TT) {
            size_t g1 = (size_t)((t + 1) * BATCH + b0) * HID + j;
            #pragma unroll
            for (int i = 0; i < 4; i++) {
                ngr[i] = ggr[g1 + (size_t)i * HID];
                ngz[i] = ggz[g1 + (size_t)i * HID];
                ngn[i] = dout[g1 + (size_t)i * HID];
            }
        }

        // partial GEMM over this wave's K-quarter, all 4 mtiles x 3 gates
        const unsigned short* hb = hbf + (size_t)(t & 1) * BATCH * HID + kofs;
        f32x4 acc[3][4];
        #pragma unroll
        for (int g = 0; g < 3; g++)
            #pragma unroll
            for (int m = 0; m < 4; m++)
                acc[g][m] = f32x4{0.f, 0.f, 0.f, 0.f};
        #pragma unroll
        for (int kk = 0; kk < 8; kk++) {
            bf16x8 af[4];
            #pragma unroll
            for (int m = 0; m < 4; m++)
                af[m] = *(const bf16x8*)(hb + (size_t)(m*16 + l16) * HID + kk*32);
            #pragma unroll
            for (int m = 0; m < 4; m++) {
                acc[0][m] = __builtin_amdgcn_mfma_f32_16x16x32_bf16(af[m], wr[kk], acc[0][m], 0, 0, 0);
                acc[1][m] = __builtin_amdgcn_mfma_f32_16x16x32_bf16(af[m], wz[kk], acc[1][m], 0, 0, 0);
                acc[2][m] = __builtin_amdgcn_mfma_f32_16x16x32_bf16(af[m], wn[kk], acc[2][m], 0, 0, 0);
            }
        }

        // cross-wave K reduction via LDS (compile-time indices only on acc)
        #pragma unroll
        for (int g = 0; g < 3; g++)
            #pragma unroll
            for (int m = 0; m < 4; m++)
                red[g][m][w][lane] = acc[g][m];
        __syncthreads();
        f32x4 own[3];
        #pragma unroll
        for (int g = 0; g < 3; g++) {
            own[g] = red[g][w][0][lane];
            #pragma unroll
            for (int s = 1; s < 4; s++)
                own[g] += red[g][w][s][lane];
        }

        // epilogue: own mtile = w, rows b0..b0+3, col j
        unsigned short* hnext = hbf + (size_t)((t + 1) & 1) * BATCH * HID;
        size_t orow = (size_t)(t * BATCH + b0) * HID + j;
        #pragma unroll
        for (int i = 0; i < 4; i++) {
            float r  = 1.f / (1.f + __expf(-(cgr[i] + own[0][i] + bhr)));
            float z  = 1.f / (1.f + __expf(-(cgz[i] + own[1][i] + bhz)));
            float nv = cgn[i] + r * (own[2][i] + bhn);
            float th = 1.f - 2.f / (1.f + __expf(2.f * nv));   // tanh(nv)
            float hv = (1.f - z) * th + z * hp[i];
            hp[i] = hv;
            dout[orow + (size_t)i * HID] = hv;
            hnext[(size_t)(b0 + i) * HID + j] = f2b(hv);
        }
        if (t == TT - 1) {
            #pragma unroll
            for (int i = 0; i < 4; i++)
                dout[(size_t)TT * BATCH * HID + (size_t)(b0 + i) * HID + j] = hp[i];
            break;   // no one consumes hnext; skip last barrier
        }
        #pragma unroll
        for (int i = 0; i < 4; i++) { cgr[i] = ngr[i]; cgz[i] = ngz[i]; cgn[i] = ngn[i]; }

        // ---- flattened grid barrier ----
        __syncthreads();   // all stores issued to L2 (write-through L1), LDS reads done
        if (tid == 0) {
            __builtin_amdgcn_fence(__ATOMIC_RELEASE, "agent");   // writeback dirty L2 once
            atomicAdd(arrive, 1);                                // fire-and-forget, relaxed
            int target = 64 * (t + 1);
            while (__hip_atomic_load(arrive, __ATOMIC_RELAXED,
                                     __HIP_MEMORY_SCOPE_AGENT) < target)
                __builtin_amdgcn_s_sleep(1);
            __builtin_amdgcn_fence(__ATOMIC_ACQUIRE, "agent");   // invalidate once
        }
        __syncthreads();
    }
}

// ---------------------------------------------------------------------------
extern "C" void kernel_launch(void* const* d_in, const int* in_sizes, int n_in,
                              void* d_out, int out_size, void* d_ws, size_t ws_size,
                              hipStream_t stream)
{
    const float* x    = (const float*)d_in[0];
    const float* W_ir = (const float*)d_in[1];
    const float* b_ir = (const float*)d_in[2];
    const float* W_hr = (const float*)d_in[3];
    const float* b_hr = (const float*)d_in[4];
    const float* W_iz = (const float*)d_in[5];
    const float* b_iz = (const float*)d_in[6];
    const float* W_hz = (const float*)d_in[7];
    const float* b_hz = (const float*)d_in[8];
    const float* W_in = (const float*)d_in[9];
    const float* b_in = (const float*)d_in[10];
    const float* W_hn = (const float*)d_in[11];
    const float* b_hn = (const float*)d_in[12];
    float* out = (float*)d_out;

    char* ws = (char*)d_ws;
    size_t off = 0;
    auto alloc = [&](size_t bytes) -> char* {
        char* p = ws + off;
        off += (bytes + 255) & ~(size_t)255;
        return p;
    };
    float*          ggr      = (float*)alloc((size_t)TT * BATCH * HID * 4);
    float*          ggz      = (float*)alloc((size_t)TT * BATCH * HID * 4);
    unsigned short* wxT      = (unsigned short*)alloc((size_t)3 * HID * KDIM * 2);
    unsigned short* whT      = (unsigned short*)alloc((size_t)3 * HID * KDIM * 2);
    float*          bias_x   = (float*)alloc(3 * HID * 4);
    float*          bias_h   = (float*)alloc(3 * HID * 4);
    unsigned short* hbf      = (unsigned short*)alloc((size_t)2 * BATCH * HID * 2);
    int*            arrive   = (int*)alloc(256);

    k_init<<<64, 256, 0, stream>>>(b_ir, b_iz, b_in, b_hr, b_hz, b_hn,
                                   bias_x, bias_h, hbf, arrive);
    k_trans<<<dim3(32, 32, 6), dim3(32, 8), 0, stream>>>(W_ir, W_iz, W_in,
                                                         W_hr, W_hz, W_hn, wxT, whT);
    k_gemm_x<<<dim3(256, 24), 256, 0, stream>>>(x, wxT, bias_x, ggr, ggz, out);
    k_recur<<<64, 256, 0, stream>>>(ggr, ggz, out, whT, bias_h, hbf, arrive);
}

// Round 3
// 2949.479 us; speedup vs baseline: 2.3839x; 2.0083x over previous
//
#include <hip/hip_runtime.h>
#include <cstdint>
#include <cstddef>

#define TT   512
#define BATCH 64
#define HID  1024
#define KDIM 1024

typedef short bf16x8 __attribute__((ext_vector_type(8)));
typedef float f32x4 __attribute__((ext_vector_type(4)));

__device__ __forceinline__ unsigned short f2b(float f) {
    unsigned int u = __float_as_uint(f);
    u = (u + 0x7fffu + ((u >> 16) & 1u)) >> 16;
    return (unsigned short)u;
}

// ---------------------------------------------------------------------------
// init: concat biases, zero h buffers + flags
// ---------------------------------------------------------------------------
__global__ __launch_bounds__(256) void k_init(
    const float* __restrict__ b_ir, const float* __restrict__ b_iz, const float* __restrict__ b_in,
    const float* __restrict__ b_hr, const float* __restrict__ b_hz, const float* __restrict__ b_hn,
    float* __restrict__ bias_x, float* __restrict__ bias_h,
    unsigned short* __restrict__ hbf, int* __restrict__ flags)
{
    int gid = blockIdx.x * 256 + threadIdx.x;          // grid 64x256 = 16384
    if (gid < HID) {
        bias_x[gid]        = b_ir[gid];
        bias_x[HID + gid]  = b_iz[gid];
        bias_x[2*HID + gid]= b_in[gid];
        bias_h[gid]        = b_hr[gid];
        bias_h[HID + gid]  = b_hz[gid];
        bias_h[2*HID + gid]= b_hn[gid];
    }
    // zero both h bf16 buffers: 2*64*1024 ushorts = 32768 ushort4
    ushort4 z4 = make_ushort4(0, 0, 0, 0);
    ushort4* p = reinterpret_cast<ushort4*>(hbf);
    p[2*gid]   = z4;
    p[2*gid+1] = z4;
    if (gid < 256 * 16) flags[gid] = 0;                // 256 flags, 64B-padded
}

// ---------------------------------------------------------------------------
// transpose W[k][j] (fp32) -> wT[n][k] (bf16), n = gate*1024 + j
// grid (32, 32, 6), block (32, 8)
// ---------------------------------------------------------------------------
__global__ __launch_bounds__(256) void k_trans(
    const float* __restrict__ w0, const float* __restrict__ w1, const float* __restrict__ w2,
    const float* __restrict__ w3, const float* __restrict__ w4, const float* __restrict__ w5,
    unsigned short* __restrict__ wxT, unsigned short* __restrict__ whT)
{
    __shared__ float tile[32][33];
    int z = blockIdx.z;
    const float* src = (z == 0) ? w0 : (z == 1) ? w1 : (z == 2) ? w2
                     : (z == 3) ? w3 : (z == 4) ? w4 : w5;
    unsigned short* dst = (z < 3) ? (wxT + (size_t)z * HID * KDIM)
                                  : (whT + (size_t)(z - 3) * HID * KDIM);
    int kb = blockIdx.x * 32, jb = blockIdx.y * 32;
    int tx = threadIdx.x, ty = threadIdx.y;
    #pragma unroll
    for (int p = 0; p < 4; p++)
        tile[tx][ty + 8*p] = src[(size_t)(kb + ty + 8*p) * HID + jb + tx];
    __syncthreads();
    #pragma unroll
    for (int p = 0; p < 4; p++) {
        int n = jb + ty + 8*p;
        dst[(size_t)n * KDIM + kb + tx] = f2b(tile[ty + 8*p][tx]);
    }
}

// ---------------------------------------------------------------------------
// GEMM A: gates = x @ [W_ir|W_iz|W_in] + bias.  M=32768, N=3072, K=1024.
// ---------------------------------------------------------------------------
#define BM 128
#define BN 128
#define LDA 72   // 64 + 8 pad, in ushorts (144 B rows, 16B-aligned)

__global__ __launch_bounds__(256, 2) void k_gemm_x(
    const float* __restrict__ x,            // [32768][1024] fp32
    const unsigned short* __restrict__ wxT, // [3072][1024] bf16
    const float* __restrict__ biasx,        // [3072]
    float* __restrict__ ggr, float* __restrict__ ggz, float* __restrict__ ggn)
{
    __shared__ unsigned short lA[BM * LDA];
    __shared__ unsigned short lB[BN * LDA];
    int tid  = threadIdx.x;
    int wave = tid >> 6, lane = tid & 63;
    int l16  = lane & 15, lhi = lane >> 4;
    int rbase = blockIdx.x * BM;
    int nbase = blockIdx.y * BN;
    int wm = (wave >> 1) * 64, wn = (wave & 1) * 64;

    f32x4 acc[4][4];
    for (int a = 0; a < 4; a++)
        for (int b = 0; b < 4; b++)
            acc[a][b] = f32x4{0.f, 0.f, 0.f, 0.f};

    int arow = tid >> 4;          // 16 rows/pass, 8 passes
    int acol = (tid & 15) * 4;    // float4 within 64 floats
    int brow = tid >> 3;          // 32 rows/pass, 4 passes
    int bcol = (tid & 7) * 8;     // 8 shorts within 64

    for (int kb = 0; kb < KDIM; kb += 64) {
        __syncthreads();
        #pragma unroll
        for (int p = 0; p < 8; p++) {
            int r = p * 16 + arow;
            float4 v = *(const float4*)(x + (size_t)(rbase + r) * KDIM + kb + acol);
            ushort4 s;
            s.x = f2b(v.x); s.y = f2b(v.y); s.z = f2b(v.z); s.w = f2b(v.w);
            *(ushort4*)(lA + r * LDA + acol) = s;
        }
        #pragma unroll
        for (int p = 0; p < 4; p++) {
            int r = p * 32 + brow;
            bf16x8 v = *(const bf16x8*)(wxT + (size_t)(nbase + r) * KDIM + kb + bcol);
            *(bf16x8*)(lB + r * LDA + bcol) = v;
        }
        __syncthreads();
        #pragma unroll
        for (int kk = 0; kk < 2; kk++) {
            bf16x8 af[4], bfr[4];
            #pragma unroll
            for (int mt = 0; mt < 4; mt++)
                af[mt] = *(const bf16x8*)(lA + (wm + mt*16 + l16) * LDA + kk*32 + lhi*8);
            #pragma unroll
            for (int nt = 0; nt < 4; nt++)
                bfr[nt] = *(const bf16x8*)(lB + (wn + nt*16 + l16) * LDA + kk*32 + lhi*8);
            #pragma unroll
            for (int mt = 0; mt < 4; mt++)
                #pragma unroll
                for (int nt = 0; nt < 4; nt++)
                    acc[mt][nt] = __builtin_amdgcn_mfma_f32_16x16x32_bf16(
                        af[mt], bfr[nt], acc[mt][nt], 0, 0, 0);
        }
    }
    // epilogue: C/D layout col=lane&15 (N), row=(lane>>4)*4+i (M)
    #pragma unroll
    for (int nt = 0; nt < 4; nt++) {
        int n = nbase + wn + nt*16 + l16;
        float bv = biasx[n];
        int g = n >> 10;
        int j = n & 1023;
        float* outp = (g == 0) ? ggr : (g == 1) ? ggz : ggn;
        #pragma unroll
        for (int mt = 0; mt < 4; mt++) {
            #pragma unroll
            for (int i = 0; i < 4; i++) {
                int R = rbase + wm + mt*16 + lhi*4 + i;        // R = b*512 + t
                size_t orow = (size_t)((R & 511) * BATCH + (R >> 9));
                outp[orow * HID + j] = acc[mt][nt][i] + bv;
            }
        }
    }
}

// ---------------------------------------------------------------------------
// Recurrence: persistent, 256 blocks x 256 thr (1 block/CU on all 256 CUs).
// Block = 16 cols (c=blk>>2) x 16 batch rows (q=blk&3). Waves split K
// (256 each); weights register-resident (24 bf16x8/lane). LDS reduce; one
// output element per thread. NO fences, NO atomicAdd: h + flags exchanged
// via relaxed agent-scope atomics (write-through to LLC / LLC-fetch);
// producer ordering via __syncthreads' vmcnt(0) drain before flag store;
// consumers poll 256 per-block flags with 4 vector loads + __all.
// ---------------------------------------------------------------------------
__global__ __launch_bounds__(256, 1) void k_recur(
    const float* __restrict__ ggr, const float* __restrict__ ggz,
    float* __restrict__ dout,                // [T][B][H] (gn preloaded) + tail [B][H]
    const unsigned short* __restrict__ whT,  // [3072][1024] bf16
    const float* __restrict__ biash,         // [3072]
    unsigned short* __restrict__ hbf,        // [2][64][1024] bf16
    int* __restrict__ flags)                 // [256] stride-16 ints (64 B lines)
{
    __shared__ float red[3 * 4 * 64 * 4];        // 12 KB: gate, wave, lane, reg
    __shared__ unsigned long long hsu[64];       // 512 B: 16x16 bf16 h tile
    unsigned short* hsp = (unsigned short*)hsu;

    int tid  = threadIdx.x;
    int w    = tid >> 6, lane = tid & 63;
    int l16  = lane & 15, lhi = lane >> 4;
    int blk  = blockIdx.x;
    int q    = blk & 3;            // batch quarter (rows q*16 .. q*16+15)
    int c    = blk >> 2;           // column group (cols c*16 .. c*16+15)
    int row  = tid >> 4;           // epilogue row 0..15
    int col  = tid & 15;           // epilogue col 0..15
    int j_l  = c * 16 + l16;       // mfma lane's column
    int j_t  = c * 16 + col;       // epilogue thread's column
    int b_t  = q * 16 + row;       // epilogue thread's batch row
    int kbase = w * 256 + lhi * 8; // this lane's K base

    // loop-invariant weight fragments -> registers (24 x bf16x8 = 96 VGPR)
    bf16x8 wr[8], wz[8], wn[8];
    {
        const unsigned short* base = whT + (size_t)j_l * KDIM + kbase;
        #pragma unroll
        for (int kk = 0; kk < 8; kk++) {
            wr[kk] = *(const bf16x8*)(base + kk*32);
            wz[kk] = *(const bf16x8*)(base + kk*32 + (size_t)HID * KDIM);
            wn[kk] = *(const bf16x8*)(base + kk*32 + (size_t)2 * HID * KDIM);
        }
    }
    float bhr = biash[j_t], bhz = biash[HID + j_t], bhn = biash[2*HID + j_t];

    float hp = 0.f;
    float cgr, cgz, cgn;
    {
        size_t g0 = (size_t)b_t * HID + j_t;    // t = 0
        cgr = ggr[g0]; cgz = ggz[g0]; cgn = dout[g0];
    }

    #pragma unroll 1
    for (int t = 0; t < TT; t++) {
        // ---- wait for step-t h (flags >= t); 4 flags per lane, no RMW ----
        if (t > 0) {
            bool ok;
            do {
                int f0 = __hip_atomic_load(&flags[(lane      ) * 16], __ATOMIC_RELAXED, __HIP_MEMORY_SCOPE_AGENT);
                int f1 = __hip_atomic_load(&flags[(lane +  64) * 16], __ATOMIC_RELAXED, __HIP_MEMORY_SCOPE_AGENT);
                int f2 = __hip_atomic_load(&flags[(lane + 128) * 16], __ATOMIC_RELAXED, __HIP_MEMORY_SCOPE_AGENT);
                int f3 = __hip_atomic_load(&flags[(lane + 192) * 16], __ATOMIC_RELAXED, __HIP_MEMORY_SCOPE_AGENT);
                ok = (f0 >= t) & (f1 >= t) & (f2 >= t) & (f3 >= t);
            } while (!__all(ok));
        }

        // ---- h fragment loads: 16 rows x this wave's K-quarter, sc1 (LLC) ----
        const unsigned short* hb = hbf + (size_t)(t & 1) * BATCH * HID
                                 + (size_t)(q * 16 + l16) * HID + kbase;
        unsigned long long hu[16];
        #pragma unroll
        for (int kk = 0; kk < 8; kk++) {
            hu[2*kk]   = __hip_atomic_load((unsigned long long*)(hb + kk*32),
                                           __ATOMIC_RELAXED, __HIP_MEMORY_SCOPE_AGENT);
            hu[2*kk+1] = __hip_atomic_load((unsigned long long*)(hb + kk*32) + 1,
                                           __ATOMIC_RELAXED, __HIP_MEMORY_SCOPE_AGENT);
        }

        // ---- gate prefetch for t+1 (plain cached loads, lands during MFMA) ----
        float ngr = 0.f, ngz = 0.f, ngn = 0.f;
        if (t + 1 < TT) {
            size_t g1 = (size_t)((t + 1) * BATCH + b_t) * HID + j_t;
            ngr = ggr[g1]; ngz = ggz[g1]; ngn = dout[g1];
        }

        // ---- partial GEMM over this wave's K-quarter (m=1 tile, 3 gates) ----
        f32x4 a0{0.f,0.f,0.f,0.f}, a1{0.f,0.f,0.f,0.f}, a2{0.f,0.f,0.f,0.f};
        #pragma unroll
        for (int kk = 0; kk < 8; kk++) {
            union { unsigned long long u[2]; bf16x8 v; } fa;
            fa.u[0] = hu[2*kk]; fa.u[1] = hu[2*kk+1];
            a0 = __builtin_amdgcn_mfma_f32_16x16x32_bf16(fa.v, wr[kk], a0, 0, 0, 0);
            a1 = __builtin_amdgcn_mfma_f32_16x16x32_bf16(fa.v, wz[kk], a1, 0, 0, 0);
            a2 = __builtin_amdgcn_mfma_f32_16x16x32_bf16(fa.v, wn[kk], a2, 0, 0, 0);
        }

        // ---- cross-wave K reduction via LDS ----
        {
            f32x4* rp = (f32x4*)red;
            rp[(0*4 + w) * 64 + lane] = a0;
            rp[(1*4 + w) * 64 + lane] = a1;
            rp[(2*4 + w) * 64 + lane] = a2;
        }
        __syncthreads();
        int lsrc = (row >> 2) * 16 + col, ri = row & 3;
        float s0 = 0.f, s1 = 0.f, s2 = 0.f;
        #pragma unroll
        for (int ww = 0; ww < 4; ww++) {
            s0 += red[((0*4 + ww) * 64 + lsrc) * 4 + ri];
            s1 += red[((1*4 + ww) * 64 + lsrc) * 4 + ri];
            s2 += red[((2*4 + ww) * 64 + lsrc) * 4 + ri];
        }

        // ---- epilogue: one element per thread ----
        float r  = 1.f / (1.f + __expf(-(cgr + s0 + bhr)));
        float z  = 1.f / (1.f + __expf(-(cgz + s1 + bhz)));
        float nv = cgn + r * (s2 + bhn);
        float th = 1.f - 2.f / (1.f + __expf(2.f * nv));   // tanh(nv)
        float hv = (1.f - z) * th + z * hp;
        hp = hv;
        dout[((size_t)t * BATCH + b_t) * HID + j_t] = hv;  // plain store (private)
        if (t == TT - 1) {
            dout[(size_t)TT * BATCH * HID + (size_t)b_t * HID + j_t] = hv;
            break;                                         // no one consumes next h
        }
        cgr = ngr; cgz = ngz; cgn = ngn;

        // ---- publish h tile: LDS pack -> 64 x 8B write-through stores ----
        hsp[row * 16 + col] = f2b(hv);
        __syncthreads();
        if (tid < 64) {
            int rr = tid >> 2, ch = tid & 3;
            unsigned long long v = hsu[rr * 4 + ch];
            unsigned long long* dst = (unsigned long long*)(
                hbf + (size_t)((t + 1) & 1) * BATCH * HID
                    + (size_t)(q * 16 + rr) * HID + c * 16 + ch * 4);
            __hip_atomic_store(dst, v, __ATOMIC_RELAXED, __HIP_MEMORY_SCOPE_AGENT);
        }
        __syncthreads();   // s_waitcnt vmcnt(0): h stores acked at LLC in all waves
        if (tid == 0)
            __hip_atomic_store(&flags[blk * 16], t + 1,
                               __ATOMIC_RELAXED, __HIP_MEMORY_SCOPE_AGENT);
    }
}

// ---------------------------------------------------------------------------
extern "C" void kernel_launch(void* const* d_in, const int* in_sizes, int n_in,
                              void* d_out, int out_size, void* d_ws, size_t ws_size,
                              hipStream_t stream)
{
    const float* x    = (const float*)d_in[0];
    const float* W_ir = (const float*)d_in[1];
    const float* b_ir = (const float*)d_in[2];
    const float* W_hr = (const float*)d_in[3];
    const float* b_hr = (const float*)d_in[4];
    const float* W_iz = (const float*)d_in[5];
    const float* b_iz = (const float*)d_in[6];
    const float* W_hz = (const float*)d_in[7];
    const float* b_hz = (const float*)d_in[8];
    const float* W_in = (const float*)d_in[9];
    const float* b_in = (const float*)d_in[10];
    const float* W_hn = (const float*)d_in[11];
    const float* b_hn = (const float*)d_in[12];
    float* out = (float*)d_out;

    char* ws = (char*)d_ws;
    size_t off = 0;
    auto alloc = [&](size_t bytes) -> char* {
        char* p = ws + off;
        off += (bytes + 255) & ~(size_t)255;
        return p;
    };
    float*          ggr      = (float*)alloc((size_t)TT * BATCH * HID * 4);
    float*          ggz      = (float*)alloc((size_t)TT * BATCH * HID * 4);
    unsigned short* wxT      = (unsigned short*)alloc((size_t)3 * HID * KDIM * 2);
    unsigned short* whT      = (unsigned short*)alloc((size_t)3 * HID * KDIM * 2);
    float*          bias_x   = (float*)alloc(3 * HID * 4);
    float*          bias_h   = (float*)alloc(3 * HID * 4);
    unsigned short* hbf      = (unsigned short*)alloc((size_t)2 * BATCH * HID * 2);
    int*            flags    = (int*)alloc(256 * 16 * 4);

    k_init<<<64, 256, 0, stream>>>(b_ir, b_iz, b_in, b_hr, b_hz, b_hn,
                                   bias_x, bias_h, hbf, flags);
    k_trans<<<dim3(32, 32, 6), dim3(32, 8), 0, stream>>>(W_ir, W_iz, W_in,
                                                         W_hr, W_hz, W_hn, wxT, whT);
    k_gemm_x<<<dim3(256, 24), 256, 0, stream>>>(x, wxT, bias_x, ggr, ggz, out);
    k_recur<<<256, 256, 0, stream>>>(ggr, ggz, out, whT, bias_h, hbf, flags);
}